// Round 1
// baseline (530.253 us; speedup 1.0000x reference)
//
#include <hip/hip_runtime.h>

// LSTM: B=8192, T=512, IN=8, H=64, OUT=1
// Strategy: per-workgroup 16-batch tile, T sequential steps.
//   gates[16,256] = [h(64)|x(8)|0-pad to 96] @ W' via mfma_f32_16x16x32_f16,
//   weights resident in VGPRs, h double-buffered through LDS (f16),
//   c in registers, activations fp32 via v_exp_f32/v_rcp_f32.
// Wave w owns hidden units [16w,16w+16): its 4 acc tiles are the i/f/g/o
// column tiles for those units -> activations fully lane-local.
// MFMA layouts (m89/m91/m120 verified):
//   A[m=lane&15][k=(lane>>4)*8+j], B[k=(lane>>4)*8+j][n=lane&15],
//   C/D: col=lane&15, row=(lane>>4)*4+reg.

typedef _Float16 f16_t;
typedef _Float16 half8 __attribute__((ext_vector_type(8)));
typedef float floatx4 __attribute__((ext_vector_type(4)));

#define Bn 8192
#define Tn 512
#define INn 8
#define Hn 64
#define BT 16
// LDS row strides in f16 units, padded so 16-lane b128 reads are <=2-way
// bank-aliased (144B = 36 words -> stride 4 banks; 80B = 20 words).
#define HSTRIDE 72
#define XSTRIDE 40

__global__ __launch_bounds__(256, 2)
void lstm_fused(const float* __restrict__ xg,
                const float* __restrict__ W_ih,
                const float* __restrict__ W_hh,
                const float* __restrict__ b_ih,
                const float* __restrict__ b_hh,
                const float* __restrict__ W_fc,
                const float* __restrict__ b_fc,
                float* __restrict__ out)
{
  __shared__ alignas(16) f16_t hbuf[2][BT][HSTRIDE];
  __shared__ alignas(16) f16_t xbuf[2][BT][XSTRIDE];

  const int tid   = threadIdx.x;
  const int wv    = tid >> 6;     // wave 0..3 -> hidden units 16w..16w+15
  const int lane  = tid & 63;
  const int n     = lane & 15;    // A-row (batch) / B-col / D-col index
  const int q     = lane >> 4;    // quad
  const int bbase = blockIdx.x * BT;

  // ---- B fragments (weights), resident in VGPRs for the whole T loop.
  // Tile g in {i,f,g,o}: gate column C = 64*g + 16*wv + n.
  // K layout: k in [0,64) = W_hh cols, [64,72) = W_ih cols, [72,96) = 0.
  half8 bf[4][3];
  #pragma unroll
  for (int g = 0; g < 4; ++g) {
    const int C = g * 64 + wv * 16 + n;
    #pragma unroll
    for (int c = 0; c < 3; ++c) {
      half8 v;
      #pragma unroll
      for (int j = 0; j < 8; ++j) {
        const int k = c * 32 + q * 8 + j;
        float w = 0.f;
        if (k < Hn)            w = W_hh[C * Hn + k];
        else if (k < Hn + INn) w = W_ih[C * INn + (k - Hn)];
        v[j] = (f16_t)w;
      }
      bf[g][c] = v;
    }
  }

  // ---- biases pre-scaled for exp2-based activations
  const float LOG2E = 1.4426950408889634f;
  const int u = wv * 16 + n;  // this lane's hidden unit
  const float pb_i = -(b_ih[u]       + b_hh[u])       * LOG2E;
  const float pb_f = -(b_ih[64 + u]  + b_hh[64 + u])  * LOG2E;
  const float pb_g =  (b_ih[128 + u] + b_hh[128 + u]) * (2.f * LOG2E);
  const float pb_o = -(b_ih[192 + u] + b_hh[192 + u]) * LOG2E;

  // ---- LDS init: h0 = 0 in hbuf[0]; zero x pads (cols 8..31) in both bufs
  for (int i = tid; i < 2 * BT * HSTRIDE; i += 256) ((f16_t*)hbuf)[i] = (f16_t)0.f;
  for (int i = tid; i < 2 * BT * XSTRIDE; i += 256) ((f16_t*)xbuf)[i] = (f16_t)0.f;
  __syncthreads();

  // x(t=0) into xbuf[0]: each wave loads 4 rows, lanes 0..7: (row, 16B half)
  if (lane < 8) {
    const int row = wv * 4 + (lane >> 1);
    const int hf  = lane & 1;
    const float4 xv = *(const float4*)(xg + ((size_t)(bbase + row) * Tn) * INn + hf * 4);
    f16_t* dst = &xbuf[0][row][hf * 4];
    dst[0] = (f16_t)xv.x; dst[1] = (f16_t)xv.y;
    dst[2] = (f16_t)xv.z; dst[3] = (f16_t)xv.w;
  }
  __syncthreads();

  float cst[4] = {0.f, 0.f, 0.f, 0.f};  // cell state: batch rows q*4+r, unit u

  #pragma unroll 2
  for (int t = 0; t < Tn; ++t) {
    const int p  = t & 1;
    const int pn = p ^ 1;

    // A fragments: h chunks (k 0..31, 32..63) and x chunk (k 64..95)
    const half8 a0 = *(const half8*)&hbuf[p][n][q * 8];
    const half8 a1 = *(const half8*)&hbuf[p][n][32 + q * 8];
    const half8 a2 = *(const half8*)&xbuf[p][n][q * 8];

    // prefetch x(t+1) while we compute step t
    float4 xv;
    const int  xrow = wv * 4 + (lane >> 1);
    const int  xhf  = lane & 1;
    const bool do_x = (lane < 8) && (t + 1 < Tn);
    if (do_x)
      xv = *(const float4*)(xg + ((size_t)(bbase + xrow) * Tn + (t + 1)) * INn + xhf * 4);

    floatx4 z = {0.f, 0.f, 0.f, 0.f};
    floatx4 ai = z, af = z, ag = z, ao = z;
    ai = __builtin_amdgcn_mfma_f32_16x16x32_f16(a0, bf[0][0], ai, 0, 0, 0);
    ai = __builtin_amdgcn_mfma_f32_16x16x32_f16(a1, bf[0][1], ai, 0, 0, 0);
    ai = __builtin_amdgcn_mfma_f32_16x16x32_f16(a2, bf[0][2], ai, 0, 0, 0);
    af = __builtin_amdgcn_mfma_f32_16x16x32_f16(a0, bf[1][0], af, 0, 0, 0);
    af = __builtin_amdgcn_mfma_f32_16x16x32_f16(a1, bf[1][1], af, 0, 0, 0);
    af = __builtin_amdgcn_mfma_f32_16x16x32_f16(a2, bf[1][2], af, 0, 0, 0);
    ag = __builtin_amdgcn_mfma_f32_16x16x32_f16(a0, bf[2][0], ag, 0, 0, 0);
    ag = __builtin_amdgcn_mfma_f32_16x16x32_f16(a1, bf[2][1], ag, 0, 0, 0);
    ag = __builtin_amdgcn_mfma_f32_16x16x32_f16(a2, bf[2][2], ag, 0, 0, 0);
    ao = __builtin_amdgcn_mfma_f32_16x16x32_f16(a0, bf[3][0], ao, 0, 0, 0);
    ao = __builtin_amdgcn_mfma_f32_16x16x32_f16(a1, bf[3][1], ao, 0, 0, 0);
    ao = __builtin_amdgcn_mfma_f32_16x16x32_f16(a2, bf[3][2], ao, 0, 0, 0);

    // activations (fp32), c update, h -> f16 -> hbuf[pn]
    float hv[4];
    #pragma unroll
    for (int r = 0; r < 4; ++r) {
      const float zi = ai[r], zf = af[r], zg = ag[r], zo = ao[r];
      const float si = __builtin_amdgcn_rcpf(
          1.f + __builtin_amdgcn_exp2f(__builtin_fmaf(zi, -LOG2E, pb_i)));
      const float sf = __builtin_amdgcn_rcpf(
          1.f + __builtin_amdgcn_exp2f(__builtin_fmaf(zf, -LOG2E, pb_f)));
      const float so = __builtin_amdgcn_rcpf(
          1.f + __builtin_amdgcn_exp2f(__builtin_fmaf(zo, -LOG2E, pb_o)));
      const float Eg = __builtin_amdgcn_exp2f(__builtin_fmaf(zg, 2.f * LOG2E, pb_g));
      const float tg = __builtin_fmaf(-2.f, __builtin_amdgcn_rcpf(Eg + 1.f), 1.f);
      const float cc = __builtin_fmaf(sf, cst[r], si * tg);
      cst[r] = cc;
      const float Ec = __builtin_amdgcn_exp2f(cc * (2.f * LOG2E));
      const float tc = __builtin_fmaf(-2.f, __builtin_amdgcn_rcpf(Ec + 1.f), 1.f);
      hv[r] = so * tc;
    }
    #pragma unroll
    for (int r = 0; r < 4; ++r)
      hbuf[pn][q * 4 + r][u] = (f16_t)hv[r];

    if (do_x) {
      f16_t* dst = &xbuf[pn][xrow][xhf * 4];
      dst[0] = (f16_t)xv.x; dst[1] = (f16_t)xv.y;
      dst[2] = (f16_t)xv.z; dst[3] = (f16_t)xv.w;
    }
    __syncthreads();
  }

  // ---- epilogue: out[b] = h_T[b,:] . W_fc + b_fc   (h_T is in hbuf[0])
  if (tid < 64) {
    const int b = lane & 15;
    const int part = lane >> 4;
    float s = 0.f;
    #pragma unroll
    for (int k = 0; k < 16; ++k) {
      const int uu = part * 16 + k;
      s = __builtin_fmaf((float)hbuf[0][b][uu], W_fc[uu], s);
    }
    s += __shfl_down(s, 32);
    s += __shfl_down(s, 16);
    if (lane < 16) out[bbase + b] = s + b_fc[0];
  }
}

extern "C" void kernel_launch(void* const* d_in, const int* in_sizes, int n_in,
                              void* d_out, int out_size, void* d_ws, size_t ws_size,
                              hipStream_t stream) {
  const float* x    = (const float*)d_in[0];
  const float* W_ih = (const float*)d_in[1];
  const float* W_hh = (const float*)d_in[2];
  const float* b_ih = (const float*)d_in[3];
  const float* b_hh = (const float*)d_in[4];
  const float* W_fc = (const float*)d_in[5];
  const float* b_fc = (const float*)d_in[6];
  float* out = (float*)d_out;
  dim3 grid(Bn / BT), block(256);
  hipLaunchKernelGGL(lstm_fused, grid, block, 0, stream,
                     x, W_ih, W_hh, b_ih, b_hh, W_fc, b_fc, out);
}

// Round 3
// 516.000 us; speedup vs baseline: 1.0276x; 1.0276x over previous
//
#include <hip/hip_runtime.h>

// LSTM: B=8192, T=512, IN=8, H=64, OUT=1
// R2: (a) activation scale+bias folded into MFMA (weights pre-scaled by
//     -log2e / +2log2e, accumulator initialized with scaled bias),
//     (b) x path via registers + cvt_pkrtz: no LDS round-trip; a2 values on
//     quads 1..3 multiply zero weight columns (k>=72) so no masking needed.
// R3: fix cvt_pkrtz return type (__fp16 vector, not _Float16 vector).
// Wave w owns hidden units [16w,16w+16). h double-buffered through LDS (f16),
// c in registers. MFMA layouts (m89/m91/m120 verified):
//   A[m=lane&15][k=(lane>>4)*8+j], B[k=(lane>>4)*8+j][n=lane&15],
//   C/D: col=lane&15, row=(lane>>4)*4+reg.

typedef _Float16 f16_t;
typedef _Float16 half8 __attribute__((ext_vector_type(8)));
typedef __fp16 fp16x2 __attribute__((ext_vector_type(2)));
typedef float floatx4 __attribute__((ext_vector_type(4)));

#define Bn 8192
#define Tn 512
#define INn 8
#define Hn 64
#define BT 16
#define HSTRIDE 72   // f16 units; 36 words -> a0/a1 b128 reads are 2-way (free)

__global__ __launch_bounds__(256, 2)
void lstm_fused(const float* __restrict__ xg,
                const float* __restrict__ W_ih,
                const float* __restrict__ W_hh,
                const float* __restrict__ b_ih,
                const float* __restrict__ b_hh,
                const float* __restrict__ W_fc,
                const float* __restrict__ b_fc,
                float* __restrict__ out)
{
  __shared__ alignas(16) f16_t hbuf[2][BT][HSTRIDE];

  const int tid   = threadIdx.x;
  const int wv    = tid >> 6;     // wave 0..3 -> hidden units 16w..16w+15
  const int lane  = tid & 63;
  const int n     = lane & 15;    // A-row (batch) / B-col / D-col index
  const int q     = lane >> 4;    // quad
  const int bbase = blockIdx.x * BT;

  const float LOG2E = 1.4426950408889634f;

  // ---- B fragments (weights), pre-scaled, resident in VGPRs.
  // Gate g in {i,f,g,o}: column C = 64*g + 16*wv + n.
  // K layout: k in [0,64) = W_hh cols, [64,72) = W_ih cols, [72,96) = 0.
  // Scale: i/f/o rows by -log2e (sigmoid arg), g rows by +2log2e (tanh arg).
  half8 bf[4][3];
  #pragma unroll
  for (int g = 0; g < 4; ++g) {
    const float sc = (g == 2) ? (2.f * LOG2E) : (-LOG2E);
    const int C = g * 64 + wv * 16 + n;
    #pragma unroll
    for (int c = 0; c < 3; ++c) {
      half8 v;
      #pragma unroll
      for (int j = 0; j < 8; ++j) {
        const int k = c * 32 + q * 8 + j;
        float w = 0.f;
        if (k < Hn)            w = W_hh[C * Hn + k] * sc;
        else if (k < Hn + INn) w = W_ih[C * INn + (k - Hn)] * sc;
        v[j] = (f16_t)w;
      }
      bf[g][c] = v;
    }
  }

  // ---- scaled biases -> accumulator init values
  const int u = wv * 16 + n;  // this lane's hidden unit (acc column)
  const float pb_i = -(b_ih[u]       + b_hh[u])       * LOG2E;
  const float pb_f = -(b_ih[64 + u]  + b_hh[64 + u])  * LOG2E;
  const float pb_g =  (b_ih[128 + u] + b_hh[128 + u]) * (2.f * LOG2E);
  const float pb_o = -(b_ih[192 + u] + b_hh[192 + u]) * LOG2E;
  const floatx4 bi = {pb_i, pb_i, pb_i, pb_i};
  const floatx4 bfv = {pb_f, pb_f, pb_f, pb_f};
  const floatx4 bg = {pb_g, pb_g, pb_g, pb_g};
  const floatx4 bo = {pb_o, pb_o, pb_o, pb_o};

  // ---- LDS init: h0 = 0 in hbuf[0]
  for (int i = tid; i < BT * HSTRIDE; i += 256) ((f16_t*)hbuf[0])[i] = (f16_t)0.f;
  __syncthreads();

  // ---- x pointer for this lane's batch row (same across quads -> coalesced)
  const float* xp = xg + (size_t)(bbase + n) * Tn * INn;
  float4 xa = *(const float4*)(xp);
  float4 xb = *(const float4*)(xp + 4);

  float cst[4] = {0.f, 0.f, 0.f, 0.f};  // cell state: rows q*4+r, unit u

  #pragma unroll 2
  for (int t = 0; t < Tn; ++t) {
    const int p  = t & 1;
    const int pn = p ^ 1;

    // A fragments: h chunks (k 0..31, 32..63) from LDS
    const half8 a0 = *(const half8*)&hbuf[p][n][q * 8];
    const half8 a1 = *(const half8*)&hbuf[p][n][32 + q * 8];

    // a2 from registers (quads>0 hold don't-care values: weights are 0 there)
    union { half8 v; fp16x2 h2[4]; } A2;
    A2.h2[0] = __builtin_amdgcn_cvt_pkrtz(xa.x, xa.y);
    A2.h2[1] = __builtin_amdgcn_cvt_pkrtz(xa.z, xa.w);
    A2.h2[2] = __builtin_amdgcn_cvt_pkrtz(xb.x, xb.y);
    A2.h2[3] = __builtin_amdgcn_cvt_pkrtz(xb.z, xb.w);
    const half8 a2 = A2.v;

    // prefetch x(t+1) while we compute step t (uniform clamp, no branch)
    const int tnx = (t + 1 < Tn) ? (t + 1) : 0;
    const float4 xan = *(const float4*)(xp + (size_t)tnx * INn);
    const float4 xbn = *(const float4*)(xp + (size_t)tnx * INn + 4);

    floatx4 ai = bi, af = bfv, ag = bg, ao = bo;
    ai = __builtin_amdgcn_mfma_f32_16x16x32_f16(a0, bf[0][0], ai, 0, 0, 0);
    ai = __builtin_amdgcn_mfma_f32_16x16x32_f16(a1, bf[0][1], ai, 0, 0, 0);
    ai = __builtin_amdgcn_mfma_f32_16x16x32_f16(a2, bf[0][2], ai, 0, 0, 0);
    af = __builtin_amdgcn_mfma_f32_16x16x32_f16(a0, bf[1][0], af, 0, 0, 0);
    af = __builtin_amdgcn_mfma_f32_16x16x32_f16(a1, bf[1][1], af, 0, 0, 0);
    af = __builtin_amdgcn_mfma_f32_16x16x32_f16(a2, bf[1][2], af, 0, 0, 0);
    ag = __builtin_amdgcn_mfma_f32_16x16x32_f16(a0, bf[2][0], ag, 0, 0, 0);
    ag = __builtin_amdgcn_mfma_f32_16x16x32_f16(a1, bf[2][1], ag, 0, 0, 0);
    ag = __builtin_amdgcn_mfma_f32_16x16x32_f16(a2, bf[2][2], ag, 0, 0, 0);
    ao = __builtin_amdgcn_mfma_f32_16x16x32_f16(a0, bf[3][0], ao, 0, 0, 0);
    ao = __builtin_amdgcn_mfma_f32_16x16x32_f16(a1, bf[3][1], ao, 0, 0, 0);
    ao = __builtin_amdgcn_mfma_f32_16x16x32_f16(a2, bf[3][2], ao, 0, 0, 0);

    // activations (acc already holds exp2 argument incl. bias)
    float hv[4];
    #pragma unroll
    for (int r = 0; r < 4; ++r) {
      const float si = __builtin_amdgcn_rcpf(1.f + __builtin_amdgcn_exp2f(ai[r]));
      const float sf = __builtin_amdgcn_rcpf(1.f + __builtin_amdgcn_exp2f(af[r]));
      const float so = __builtin_amdgcn_rcpf(1.f + __builtin_amdgcn_exp2f(ao[r]));
      const float tg = __builtin_fmaf(
          -2.f, __builtin_amdgcn_rcpf(__builtin_amdgcn_exp2f(ag[r]) + 1.f), 1.f);
      const float cc = __builtin_fmaf(sf, cst[r], si * tg);
      cst[r] = cc;
      const float tc = __builtin_fmaf(
          -2.f,
          __builtin_amdgcn_rcpf(__builtin_amdgcn_exp2f(cc * (2.f * LOG2E)) + 1.f),
          1.f);
      hv[r] = so * tc;
    }
    #pragma unroll
    for (int r = 0; r < 4; ++r)
      hbuf[pn][q * 4 + r][u] = (f16_t)hv[r];

    xa = xan; xb = xbn;
    __syncthreads();
  }

  // ---- epilogue: out[b] = h_T[b,:] . W_fc + b_fc   (h_T is in hbuf[0])
  if (tid < 64) {
    const int b = lane & 15;
    const int part = lane >> 4;
    float s = 0.f;
    #pragma unroll
    for (int k = 0; k < 16; ++k) {
      const int uu = part * 16 + k;
      s = __builtin_fmaf((float)hbuf[0][b][uu], W_fc[uu], s);
    }
    s += __shfl_down(s, 32);
    s += __shfl_down(s, 16);
    if (lane < 16) out[bbase + b] = s + b_fc[0];
  }
}

extern "C" void kernel_launch(void* const* d_in, const int* in_sizes, int n_in,
                              void* d_out, int out_size, void* d_ws, size_t ws_size,
                              hipStream_t stream) {
  const float* x    = (const float*)d_in[0];
  const float* W_ih = (const float*)d_in[1];
  const float* W_hh = (const float*)d_in[2];
  const float* b_ih = (const float*)d_in[3];
  const float* b_hh = (const float*)d_in[4];
  const float* W_fc = (const float*)d_in[5];
  const float* b_fc = (const float*)d_in[6];
  float* out = (float*)d_out;
  dim3 grid(Bn / BT), block(256);
  hipLaunchKernelGGL(lstm_fused, grid, block, 0, stream,
                     x, W_ih, W_hh, b_ih, b_hh, W_fc, b_fc, out);
}

// Round 4
// 496.346 us; speedup vs baseline: 1.0683x; 1.0396x over previous
//
#include <hip/hip_runtime.h>

// LSTM: B=8192, T=512, IN=8, H=64, OUT=1
// R4: x staged through double-buffered LDS in 16-step chunks. Inner steps
//     have NO global loads -> the compiler's vmcnt(0) drain before each
//     s_barrier (m97) no longer exposes HBM/L2 latency every step.
//     a2 fragment = one broadcast ds_read_b128 (quads>0 are don't-care:
//     weight columns k>=72 are zero).
// R2: activation scale+bias folded into MFMA (weights pre-scaled by -log2e /
//     +2log2e, accumulator initialized with scaled bias).
// Wave w owns hidden units [16w,16w+16). h double-buffered through LDS (f16),
// c in registers. MFMA layouts (m89/m91/m120 verified):
//   A[m=lane&15][k=(lane>>4)*8+j], B[k=(lane>>4)*8+j][n=lane&15],
//   C/D: col=lane&15, row=(lane>>4)*4+reg.

typedef _Float16 f16_t;
typedef _Float16 half8 __attribute__((ext_vector_type(8)));
typedef __fp16 fp16x2 __attribute__((ext_vector_type(2)));
typedef float floatx4 __attribute__((ext_vector_type(4)));

#define Bn 8192
#define Tn 512
#define INn 8
#define Hn 64
#define BT 16
#define CHUNK 16
#define NCHUNK (Tn / CHUNK)
#define HSTRIDE 72    // f16; 36 words -> a0/a1 b128 reads 2-way (free)
#define XTSTRIDE 136  // f16 per tt: 16 rows * 8 + 8 pad; 68 words -> 4-bank skew

__global__ __launch_bounds__(256, 2)
void lstm_fused(const float* __restrict__ xg,
                const float* __restrict__ W_ih,
                const float* __restrict__ W_hh,
                const float* __restrict__ b_ih,
                const float* __restrict__ b_hh,
                const float* __restrict__ W_fc,
                const float* __restrict__ b_fc,
                float* __restrict__ out)
{
  __shared__ alignas(16) f16_t hbuf[2][BT][HSTRIDE];
  __shared__ alignas(16) f16_t xlds[2][CHUNK][XTSTRIDE];

  const int tid   = threadIdx.x;
  const int wv    = tid >> 6;     // wave 0..3 -> hidden units 16w..16w+15
  const int lane  = tid & 63;
  const int n     = lane & 15;    // A-row (batch) / B-col / D-col index
  const int q     = lane >> 4;    // quad
  const int bbase = blockIdx.x * BT;

  const float LOG2E = 1.4426950408889634f;

  // ---- B fragments (weights), pre-scaled, resident in VGPRs/AGPRs.
  // Gate g in {i,f,g,o}: column C = 64*g + 16*wv + n.
  // K layout: k in [0,64) = W_hh cols, [64,72) = W_ih cols, [72,96) = 0.
  half8 bf[4][3];
  #pragma unroll
  for (int g = 0; g < 4; ++g) {
    const float sc = (g == 2) ? (2.f * LOG2E) : (-LOG2E);
    const int C = g * 64 + wv * 16 + n;
    #pragma unroll
    for (int c = 0; c < 3; ++c) {
      half8 v;
      #pragma unroll
      for (int j = 0; j < 8; ++j) {
        const int k = c * 32 + q * 8 + j;
        float w = 0.f;
        if (k < Hn)            w = W_hh[C * Hn + k] * sc;
        else if (k < Hn + INn) w = W_ih[C * INn + (k - Hn)] * sc;
        v[j] = (f16_t)w;
      }
      bf[g][c] = v;
    }
  }

  // ---- scaled biases -> accumulator init values
  const int u = wv * 16 + n;  // this lane's hidden unit (acc column)
  const float pb_i = -(b_ih[u]       + b_hh[u])       * LOG2E;
  const float pb_f = -(b_ih[64 + u]  + b_hh[64 + u])  * LOG2E;
  const float pb_g =  (b_ih[128 + u] + b_hh[128 + u]) * (2.f * LOG2E);
  const float pb_o = -(b_ih[192 + u] + b_hh[192 + u]) * LOG2E;
  const floatx4 bi = {pb_i, pb_i, pb_i, pb_i};
  const floatx4 bfv = {pb_f, pb_f, pb_f, pb_f};
  const floatx4 bg = {pb_g, pb_g, pb_g, pb_g};
  const floatx4 bo = {pb_o, pb_o, pb_o, pb_o};

  // ---- LDS init: h0 = 0 in hbuf[0]
  for (int i = tid; i < BT * HSTRIDE; i += 256) ((f16_t*)hbuf[0])[i] = (f16_t)0.f;

  // ---- x staging assignment: lane -> (row, tt); 16-lane groups coalesce 512B
  const int row_s = tid >> 4;   // 0..15 batch row
  const int tt_s  = tid & 15;   // 0..15 timestep within chunk
  const float* xps = xg + ((size_t)(bbase + row_s) * Tn + tt_s) * INn;

  // preload chunk 0 into registers
  float4 pa = *(const float4*)(xps);
  float4 pb2 = *(const float4*)(xps + 4);

  float cst[4] = {0.f, 0.f, 0.f, 0.f};  // cell state: rows q*4+r, unit u

  for (int ch = 0; ch < NCHUNK; ++ch) {
    // ---- write staged chunk to LDS (f16)
    union { half8 v; fp16x2 h2[4]; } P;
    P.h2[0] = __builtin_amdgcn_cvt_pkrtz(pa.x, pa.y);
    P.h2[1] = __builtin_amdgcn_cvt_pkrtz(pa.z, pa.w);
    P.h2[2] = __builtin_amdgcn_cvt_pkrtz(pb2.x, pb2.y);
    P.h2[3] = __builtin_amdgcn_cvt_pkrtz(pb2.z, pb2.w);
    *(half8*)&xlds[ch & 1][tt_s][row_s * 8] = P.v;
    __syncthreads();  // xlds chunk + (first iter) hbuf zero visible

    // ---- prefetch next chunk (uniform clamp; latency hidden over 16 steps)
    const int chn = (ch + 1 < NCHUNK) ? (ch + 1) : 0;
    pa  = *(const float4*)(xps + (size_t)chn * CHUNK * INn);
    pb2 = *(const float4*)(xps + (size_t)chn * CHUNK * INn + 4);

    #pragma unroll
    for (int tt = 0; tt < CHUNK; ++tt) {
      const int p  = tt & 1;
      const int pn = p ^ 1;

      // A fragments: h chunks from LDS, x fragment broadcast from x panel
      const half8 a0 = *(const half8*)&hbuf[p][n][q * 8];
      const half8 a1 = *(const half8*)&hbuf[p][n][32 + q * 8];
      const half8 a2 = *(const half8*)&xlds[ch & 1][tt][n * 8];

      floatx4 ai = bi, af = bfv, ag = bg, ao = bo;
      ai = __builtin_amdgcn_mfma_f32_16x16x32_f16(a0, bf[0][0], ai, 0, 0, 0);
      ai = __builtin_amdgcn_mfma_f32_16x16x32_f16(a1, bf[0][1], ai, 0, 0, 0);
      ai = __builtin_amdgcn_mfma_f32_16x16x32_f16(a2, bf[0][2], ai, 0, 0, 0);
      af = __builtin_amdgcn_mfma_f32_16x16x32_f16(a0, bf[1][0], af, 0, 0, 0);
      af = __builtin_amdgcn_mfma_f32_16x16x32_f16(a1, bf[1][1], af, 0, 0, 0);
      af = __builtin_amdgcn_mfma_f32_16x16x32_f16(a2, bf[1][2], af, 0, 0, 0);
      ag = __builtin_amdgcn_mfma_f32_16x16x32_f16(a0, bf[2][0], ag, 0, 0, 0);
      ag = __builtin_amdgcn_mfma_f32_16x16x32_f16(a1, bf[2][1], ag, 0, 0, 0);
      ag = __builtin_amdgcn_mfma_f32_16x16x32_f16(a2, bf[2][2], ag, 0, 0, 0);
      ao = __builtin_amdgcn_mfma_f32_16x16x32_f16(a0, bf[3][0], ao, 0, 0, 0);
      ao = __builtin_amdgcn_mfma_f32_16x16x32_f16(a1, bf[3][1], ao, 0, 0, 0);
      ao = __builtin_amdgcn_mfma_f32_16x16x32_f16(a2, bf[3][2], ao, 0, 0, 0);

      // activations (acc already holds exp2 argument incl. bias)
      float hv[4];
      #pragma unroll
      for (int r = 0; r < 4; ++r) {
        const float si = __builtin_amdgcn_rcpf(1.f + __builtin_amdgcn_exp2f(ai[r]));
        const float sf = __builtin_amdgcn_rcpf(1.f + __builtin_amdgcn_exp2f(af[r]));
        const float so = __builtin_amdgcn_rcpf(1.f + __builtin_amdgcn_exp2f(ao[r]));
        const float tg = __builtin_fmaf(
            -2.f, __builtin_amdgcn_rcpf(__builtin_amdgcn_exp2f(ag[r]) + 1.f), 1.f);
        const float cc = __builtin_fmaf(sf, cst[r], si * tg);
        cst[r] = cc;
        const float tc = __builtin_fmaf(
            -2.f,
            __builtin_amdgcn_rcpf(__builtin_amdgcn_exp2f(cc * (2.f * LOG2E)) + 1.f),
            1.f);
        hv[r] = so * tc;
      }
      #pragma unroll
      for (int r = 0; r < 4; ++r)
        hbuf[pn][q * 4 + r][u] = (f16_t)hv[r];

      __syncthreads();
    }
  }

  // ---- epilogue: out[b] = h_T[b,:] . W_fc + b_fc   (h_T is in hbuf[0])
  if (tid < 64) {
    const int b = lane & 15;
    const int part = lane >> 4;
    float s = 0.f;
    #pragma unroll
    for (int k = 0; k < 16; ++k) {
      const int uu = part * 16 + k;
      s = __builtin_fmaf((float)hbuf[0][b][uu], W_fc[uu], s);
    }
    s += __shfl_down(s, 32);
    s += __shfl_down(s, 16);
    if (lane < 16) out[bbase + b] = s + b_fc[0];
  }
}

extern "C" void kernel_launch(void* const* d_in, const int* in_sizes, int n_in,
                              void* d_out, int out_size, void* d_ws, size_t ws_size,
                              hipStream_t stream) {
  const float* x    = (const float*)d_in[0];
  const float* W_ih = (const float*)d_in[1];
  const float* W_hh = (const float*)d_in[2];
  const float* b_ih = (const float*)d_in[3];
  const float* b_hh = (const float*)d_in[4];
  const float* W_fc = (const float*)d_in[5];
  const float* b_fc = (const float*)d_in[6];
  float* out = (float*)d_out;
  dim3 grid(Bn / BT), block(256);
  hipLaunchKernelGGL(lstm_fused, grid, block, 0, stream,
                     x, W_ih, W_hh, b_ih, b_hh, W_fc, b_fc, out);
}

// Round 5
// 448.481 us; speedup vs baseline: 1.1823x; 1.1067x over previous
//
#include <hip/hip_runtime.h>

// LSTM: B=8192, T=512, IN=8, H=64, OUT=1
// R5: transcendental diet. c kept in scaled domain chat = 2log2e*c:
//   chat' = [chat*(1+A)(1+G) + K(G-1)(1+F)] * rcp((1+F)(1+A)(1+G))
//   h     = (C-1) * rcp((1+O)(1+C)),  C = 2^chat'
//   (A=2^ai_acc, G=2^ag_acc, F=2^af_acc, O=2^ao_acc) -> 5 exp2 + 2 rcp per
//   element (was 5+5). Bias lives in persistent MFMA C-operand regs (no
//   per-step acc init). Full-rate math on float2 -> v_pk_*_f32.
// R4: x staged through double-buffered LDS in 16-step chunks (no inner vmem).
// R2: activation scale folded into weights (-log2e for i/f/o, +2log2e for g).
// Wave w owns hidden units [16w,16w+16). h double-buffered through LDS (f16).
// MFMA layouts (m89/m91/m120 verified):
//   A[m=lane&15][k=(lane>>4)*8+j], B[k=(lane>>4)*8+j][n=lane&15],
//   C/D: col=lane&15, row=(lane>>4)*4+reg.

typedef _Float16 f16_t;
typedef _Float16 half8 __attribute__((ext_vector_type(8)));
typedef __fp16 fp16x2 __attribute__((ext_vector_type(2)));
typedef float floatx2 __attribute__((ext_vector_type(2)));
typedef float floatx4 __attribute__((ext_vector_type(4)));

#define Bn 8192
#define Tn 512
#define INn 8
#define Hn 64
#define BT 16
#define CHUNK 16
#define NCHUNK (Tn / CHUNK)
#define HSTRIDE 72    // f16; 36 words -> a0/a1 b128 reads 2-way (free)
#define XTSTRIDE 136  // f16 per tt: 16 rows * 8 + 8 pad; 68 words -> 4-bank skew

__device__ __forceinline__ floatx2 act_pair(float zi0, float zi1,
                                            float zf0, float zf1,
                                            float zg0, float zg1,
                                            float zo0, float zo1,
                                            floatx2& chat) {
  const floatx2 one  = {1.f, 1.f};
  const float  K2   = 2.8853900817779268f;  // 2*log2(e)
  const floatx2 K2v  = {K2, K2};
  const floatx2 mK2v = {-K2, -K2};
  const floatx2 clmp = {126.f, 126.f};
  floatx2 A = {__builtin_amdgcn_exp2f(zi0), __builtin_amdgcn_exp2f(zi1)};
  floatx2 G = {__builtin_amdgcn_exp2f(zg0), __builtin_amdgcn_exp2f(zg1)};
  floatx2 F = {__builtin_amdgcn_exp2f(zf0), __builtin_amdgcn_exp2f(zf1)};
  floatx2 O = {__builtin_amdgcn_exp2f(zo0), __builtin_amdgcn_exp2f(zo1)};
  floatx2 PA  = A + one;
  floatx2 PG  = G + one;
  floatx2 PF  = F + one;
  floatx2 PAG = PA * PG;
  floatx2 num = __builtin_elementwise_fma(G, K2v, mK2v) * PF;  // K(G-1)(1+F)
  floatx2 s   = __builtin_elementwise_fma(chat, PAG, num);
  floatx2 P3  = PF * PAG;
  floatx2 R   = {__builtin_amdgcn_rcpf(P3.x), __builtin_amdgcn_rcpf(P3.y)};
  chat = __builtin_elementwise_min(s * R, clmp);
  floatx2 C2 = {__builtin_amdgcn_exp2f(chat.x), __builtin_amdgcn_exp2f(chat.y)};
  floatx2 P4 = (O + one) * (C2 + one);
  floatx2 Rh = {__builtin_amdgcn_rcpf(P4.x), __builtin_amdgcn_rcpf(P4.y)};
  return (C2 - one) * Rh;  // h = o * tanh(c)
}

__global__ __launch_bounds__(256, 2)
void lstm_fused(const float* __restrict__ xg,
                const float* __restrict__ W_ih,
                const float* __restrict__ W_hh,
                const float* __restrict__ b_ih,
                const float* __restrict__ b_hh,
                const float* __restrict__ W_fc,
                const float* __restrict__ b_fc,
                float* __restrict__ out)
{
  __shared__ alignas(16) f16_t hbuf[2][BT][HSTRIDE];
  __shared__ alignas(16) f16_t xlds[2][CHUNK][XTSTRIDE];

  const int tid   = threadIdx.x;
  const int wv    = tid >> 6;     // wave 0..3 -> hidden units 16w..16w+15
  const int lane  = tid & 63;
  const int n     = lane & 15;    // A-row (batch) / B-col / D-col index
  const int q     = lane >> 4;    // quad
  const int bbase = blockIdx.x * BT;

  const float LOG2E = 1.4426950408889634f;

  // ---- B fragments (weights), pre-scaled, resident in VGPRs/AGPRs.
  // Gate g in {i,f,g,o}: column C = 64*g + 16*wv + n.
  // K layout: k in [0,64) = W_hh cols, [64,72) = W_ih cols, [72,96) = 0.
  half8 bf[4][3];
  #pragma unroll
  for (int g = 0; g < 4; ++g) {
    const float sc = (g == 2) ? (2.f * LOG2E) : (-LOG2E);
    const int C = g * 64 + wv * 16 + n;
    #pragma unroll
    for (int c = 0; c < 3; ++c) {
      half8 v;
      #pragma unroll
      for (int j = 0; j < 8; ++j) {
        const int k = c * 32 + q * 8 + j;
        float w = 0.f;
        if (k < Hn)            w = W_hh[C * Hn + k] * sc;
        else if (k < Hn + INn) w = W_ih[C * INn + (k - Hn)] * sc;
        v[j] = (f16_t)w;
      }
      bf[g][c] = v;
    }
  }

  // ---- scaled biases -> persistent MFMA C-operand registers
  const int u = wv * 16 + n;  // this lane's hidden unit (acc column)
  const float pb_i = -(b_ih[u]       + b_hh[u])       * LOG2E;
  const float pb_f = -(b_ih[64 + u]  + b_hh[64 + u])  * LOG2E;
  const float pb_g =  (b_ih[128 + u] + b_hh[128 + u]) * (2.f * LOG2E);
  const float pb_o = -(b_ih[192 + u] + b_hh[192 + u]) * LOG2E;
  const floatx4 bi  = {pb_i, pb_i, pb_i, pb_i};
  const floatx4 bfv = {pb_f, pb_f, pb_f, pb_f};
  const floatx4 bg  = {pb_g, pb_g, pb_g, pb_g};
  const floatx4 bo  = {pb_o, pb_o, pb_o, pb_o};

  // ---- LDS init: h0 = 0 in hbuf[0]
  for (int i = tid; i < BT * HSTRIDE; i += 256) ((f16_t*)hbuf[0])[i] = (f16_t)0.f;

  // ---- x staging assignment: lane -> (row, tt); 16-lane groups coalesce 512B
  const int row_s = tid >> 4;   // 0..15 batch row
  const int tt_s  = tid & 15;   // 0..15 timestep within chunk
  const float* xps = xg + ((size_t)(bbase + row_s) * Tn + tt_s) * INn;

  // preload chunk 0 into registers
  float4 pa = *(const float4*)(xps);
  float4 pb2 = *(const float4*)(xps + 4);

  floatx2 chat01 = {0.f, 0.f};  // scaled cell state, rows q*4+{0,1}
  floatx2 chat23 = {0.f, 0.f};  // rows q*4+{2,3}

  for (int ch = 0; ch < NCHUNK; ++ch) {
    // ---- write staged chunk to LDS (f16)
    union { half8 v; fp16x2 h2[4]; } P;
    P.h2[0] = __builtin_amdgcn_cvt_pkrtz(pa.x, pa.y);
    P.h2[1] = __builtin_amdgcn_cvt_pkrtz(pa.z, pa.w);
    P.h2[2] = __builtin_amdgcn_cvt_pkrtz(pb2.x, pb2.y);
    P.h2[3] = __builtin_amdgcn_cvt_pkrtz(pb2.z, pb2.w);
    *(half8*)&xlds[ch & 1][tt_s][row_s * 8] = P.v;
    __syncthreads();  // xlds chunk + (first iter) hbuf zero visible

    // ---- prefetch next chunk (uniform clamp; latency hidden over 16 steps)
    const int chn = (ch + 1 < NCHUNK) ? (ch + 1) : 0;
    pa  = *(const float4*)(xps + (size_t)chn * CHUNK * INn);
    pb2 = *(const float4*)(xps + (size_t)chn * CHUNK * INn + 4);

    #pragma unroll
    for (int tt = 0; tt < CHUNK; ++tt) {
      const int p  = tt & 1;
      const int pn = p ^ 1;

      // A fragments: h chunks from LDS, x fragment broadcast from x panel
      const half8 a0 = *(const half8*)&hbuf[p][n][q * 8];
      const half8 a1 = *(const half8*)&hbuf[p][n][32 + q * 8];
      const half8 a2 = *(const half8*)&xlds[ch & 1][tt][n * 8];

      // bias regs as first-MFMA C operand (D != C): no per-step acc init
      floatx4 ai = __builtin_amdgcn_mfma_f32_16x16x32_f16(a0, bf[0][0], bi, 0, 0, 0);
      ai = __builtin_amdgcn_mfma_f32_16x16x32_f16(a1, bf[0][1], ai, 0, 0, 0);
      ai = __builtin_amdgcn_mfma_f32_16x16x32_f16(a2, bf[0][2], ai, 0, 0, 0);
      floatx4 af = __builtin_amdgcn_mfma_f32_16x16x32_f16(a0, bf[1][0], bfv, 0, 0, 0);
      af = __builtin_amdgcn_mfma_f32_16x16x32_f16(a1, bf[1][1], af, 0, 0, 0);
      af = __builtin_amdgcn_mfma_f32_16x16x32_f16(a2, bf[1][2], af, 0, 0, 0);
      floatx4 ag = __builtin_amdgcn_mfma_f32_16x16x32_f16(a0, bf[2][0], bg, 0, 0, 0);
      ag = __builtin_amdgcn_mfma_f32_16x16x32_f16(a1, bf[2][1], ag, 0, 0, 0);
      ag = __builtin_amdgcn_mfma_f32_16x16x32_f16(a2, bf[2][2], ag, 0, 0, 0);
      floatx4 ao = __builtin_amdgcn_mfma_f32_16x16x32_f16(a0, bf[3][0], bo, 0, 0, 0);
      ao = __builtin_amdgcn_mfma_f32_16x16x32_f16(a1, bf[3][1], ao, 0, 0, 0);
      ao = __builtin_amdgcn_mfma_f32_16x16x32_f16(a2, bf[3][2], ao, 0, 0, 0);

      const floatx2 h01 = act_pair(ai[0], ai[1], af[0], af[1],
                                   ag[0], ag[1], ao[0], ao[1], chat01);
      const floatx2 h23 = act_pair(ai[2], ai[3], af[2], af[3],
                                   ag[2], ag[3], ao[2], ao[3], chat23);

      hbuf[pn][q * 4 + 0][u] = (f16_t)h01.x;
      hbuf[pn][q * 4 + 1][u] = (f16_t)h01.y;
      hbuf[pn][q * 4 + 2][u] = (f16_t)h23.x;
      hbuf[pn][q * 4 + 3][u] = (f16_t)h23.y;

      __syncthreads();
    }
  }

  // ---- epilogue: out[b] = h_T[b,:] . W_fc + b_fc   (h_T is in hbuf[0])
  if (tid < 64) {
    const int b = lane & 15;
    const int part = lane >> 4;
    float s = 0.f;
    #pragma unroll
    for (int k = 0; k < 16; ++k) {
      const int uu = part * 16 + k;
      s = __builtin_fmaf((float)hbuf[0][b][uu], W_fc[uu], s);
    }
    s += __shfl_down(s, 32);
    s += __shfl_down(s, 16);
    if (lane < 16) out[bbase + b] = s + b_fc[0];
  }
}

extern "C" void kernel_launch(void* const* d_in, const int* in_sizes, int n_in,
                              void* d_out, int out_size, void* d_ws, size_t ws_size,
                              hipStream_t stream) {
  const float* x    = (const float*)d_in[0];
  const float* W_ih = (const float*)d_in[1];
  const float* W_hh = (const float*)d_in[2];
  const float* b_ih = (const float*)d_in[3];
  const float* b_hh = (const float*)d_in[4];
  const float* W_fc = (const float*)d_in[5];
  const float* b_fc = (const float*)d_in[6];
  float* out = (float*)d_out;
  dim3 grid(Bn / BT), block(256);
  hipLaunchKernelGGL(lstm_fused, grid, block, 0, stream,
                     x, W_ih, W_hh, b_ih, b_hh, W_fc, b_fc, out);
}